// Round 7
// baseline (707.752 us; speedup 1.0000x reference)
//
#include <hip/hip_runtime.h>
#include <math.h>

#define HH 128
#define WW 128
#define BB 4
#define HWSZ (HH*WW)
#define PW 130          // padded image width/height
#define PSZ (PW*PW)     // 16900 padded pixels

typedef __bf16 bf16_t;
typedef bf16_t bf16x8 __attribute__((ext_vector_type(8)));
typedef float  f32x16 __attribute__((ext_vector_type(16)));

__device__ __forceinline__ void split_bf16(float v, bf16_t& h, bf16_t& l) {
    h = (bf16_t)v;
    l = (bf16_t)(v - (float)h);
}
__device__ __forceinline__ float lrelu_f(float v) { return v >= 0.0f ? v : 0.1f * v; }

// ---------------------------------------------------------------------------
// pack A0 (PADDED): [xfw(64)|xc(64)|flow(2)|zeros(30)] -> [b][130x130][pl2][160]
// ---------------------------------------------------------------------------
__global__ __launch_bounds__(256)
void pack_a0_k(const float* __restrict__ xfw, const float* __restrict__ xc,
               const float* __restrict__ flow, bf16_t* __restrict__ a0)
{
    int idx = blockIdx.x * 256 + threadIdx.x;           // BB*PSZ*160
    if (idx >= BB * PSZ * 160) return;
    int c = idx % 160; int pixp = idx / 160;
    int b = pixp / PSZ; int p = pixp - b * PSZ;
    int yy = p / PW, xx = p - yy * PW;
    float v = 0.0f;
    if (yy >= 1 && yy <= HH && xx >= 1 && xx <= WW) {
        int pi = (yy - 1) * WW + (xx - 1);
        if (c < 64)       v = xfw[(size_t)(b*64 + c) * HWSZ + pi];
        else if (c < 128) v = xc [(size_t)(b*64 + c - 64) * HWSZ + pi];
        else if (c < 130) v = flow[(size_t)(b*2 + c - 128) * HWSZ + pi];
    }
    bf16_t h, l; split_bf16(v, h, l);
    size_t base = (size_t)pixp * 320 + c;
    a0[base]       = h;
    a0[base + 160] = l;
}

// ---------------------------------------------------------------------------
// zero 1-px borders of h1p/h2p (padded [b][130x130][pl2][64] bf16); runs
// every call (ws re-poisoned). 2064 border px x 16 chunks of 16B.
// ---------------------------------------------------------------------------
__global__ __launch_bounds__(256)
void zero_border_k(bf16_t* __restrict__ h1, bf16_t* __restrict__ h2)
{
    int idx = blockIdx.x * 256 + threadIdx.x;           // 2064*16 = 33024
    if (idx >= 2064 * 16) return;
    int chunk = idx & 15; int bp = idx >> 4;
    int b = bp / 516;     int rr = bp - b * 516;
    int yy, xx;
    if (rr < 130)      { yy = 0;        xx = rr; }
    else if (rr < 260) { yy = 129;      xx = rr - 130; }
    else if (rr < 388) { yy = rr - 259; xx = 0; }
    else               { yy = rr - 387; xx = 129; }
    size_t base = ((size_t)(b * PSZ + yy * PW + xx)) * 128 + chunk * 8;
    bf16x8 z = {(bf16_t)0.f,(bf16_t)0.f,(bf16_t)0.f,(bf16_t)0.f,
                (bf16_t)0.f,(bf16_t)0.f,(bf16_t)0.f,(bf16_t)0.f};
    *(bf16x8*)(h1 + base) = z;
    *(bf16x8*)(h2 + base) = z;
}

// ---------------------------------------------------------------------------
// pack conv weights: W[oc][cin][3][3] fp32 -> Wp[tap][ocP][pl][cinP] bf16
// ---------------------------------------------------------------------------
__global__ __launch_bounds__(256)
void pack_w_k(const float* __restrict__ w, bf16_t* __restrict__ wp,
              int OC, int CIN, int OCP, int CINP)
{
    int idx = blockIdx.x * 256 + threadIdx.x;
    if (idx >= 9 * OCP * CINP) return;
    int c = idx % CINP; int r = idx / CINP;
    int oc = r % OCP;   int tap = r / OCP;
    float v = (oc < OC && c < CIN) ? w[((size_t)oc * CIN + c) * 9 + tap] : 0.0f;
    bf16_t h, l; split_bf16(v, h, l);
    size_t base = (((size_t)tap * OCP + oc) * 2) * CINP + c;
    wp[base]        = h;
    wp[base + CINP] = l;
}

// ---------------------------------------------------------------------------
// pack dcn weights: dw[oc64][cin64][3][3] -> Bp[dg16][ks3][oc64][pl2][16] bf16
// ---------------------------------------------------------------------------
__global__ __launch_bounds__(256)
void pack_dw_k(const float* __restrict__ dw, bf16_t* __restrict__ Bp)
{
    int idx = blockIdx.x * 256 + threadIdx.x;
    if (idx >= 16 * 48 * 64) return;
    int oc = idx & 63; int rest = idx >> 6;
    int kk = rest % 48; int dg = rest / 48;
    int tap = kk >> 2, cg = kk & 3;
    int ks = kk >> 4,  kj = kk & 15;
    float v = (tap < 9) ? dw[((size_t)oc * 64 + dg*4 + cg) * 9 + tap] : 0.0f;
    bf16_t h, l; split_bf16(v, h, l);
    size_t base = (((size_t)(dg*3 + ks) * 64 + oc) * 2) * 16 + kj;
    Bp[base]      = h;
    Bp[base + 16] = l;
}

// ---------------------------------------------------------------------------
// transpose x NCHW fp32 -> xT NHWC fp32 [b][pix][64]
// ---------------------------------------------------------------------------
__global__ __launch_bounds__(256)
void pack_xt_k(const float* __restrict__ x, float* __restrict__ xT)
{
    __shared__ float s[64][65];
    const int tid = threadIdx.x;
    const int p0 = blockIdx.x * 64;
    const int b = p0 >> 14, pp = p0 & 16383;
    for (int i = tid; i < 4096; i += 256) {
        int c = i >> 6, p = i & 63;
        s[p][c] = x[((size_t)(b*64 + c) << 14) + pp + p];
    }
    __syncthreads();
    for (int i = tid; i < 4096; i += 256) {
        int p = i >> 6, c = i & 63;
        xT[((size_t)(b << 14) + pp + p) * 64 + c] = s[p][c];
    }
}

// ---------------------------------------------------------------------------
// MFMA implicit-GEMM 3x3 SAME conv on padded activations.
// MT = mtiles/wave, NT = ntiles (oc groups of 32) per block.
// NT=4 for conv4: each A-fragment LDS read feeds 6 MFMAs instead of 3,
// balancing the LDS pipe against the MFMA pipe (R6 showed LDS 2.3x over).
// ---------------------------------------------------------------------------
template<int CINP, int MT, int NT, int EPI>
__global__ __launch_bounds__(256, (MT == 1 ? 4 : 2))
void conv_mfma_k(const bf16_t* __restrict__ A, const bf16_t* __restrict__ Wp,
                 const float* __restrict__ bias, void* __restrict__ outv,
                 int OCP, int OC, const float* __restrict__ flow)
{
    constexpr int NKC   = CINP / 16;
    constexpr int PSTR  = 40;
    constexpr int PROWS = 8 * MT;
    constexpr int HALO  = (PROWS + 2) * 18;
    constexpr int NCH   = HALO * 4;
    const int tid  = threadIdx.x;
    const int lane = tid & 63;
    const int wv   = tid >> 6;
    const int b     = blockIdx.y;
    const int patch = blockIdx.x;
    const int y0 = (patch >> 3) * PROWS;
    const int x0 = (patch & 7) * 16;
    const int ocBase = blockIdx.z * (NT * 32);

    __shared__ __align__(16) bf16_t s_a[HALO * PSTR];

    f32x16 acc[MT][NT];
#pragma unroll
    for (int mt = 0; mt < MT; ++mt)
#pragma unroll
        for (int nt = 0; nt < NT; ++nt)
#pragma unroll
            for (int r = 0; r < 16; ++r) acc[mt][nt][r] = 0.0f;

    const int m     = lane & 31;
    const int klane = lane >> 5;
    const int row0  = wv * 2 * MT + (m >> 4);
    const int pxx   = m & 15;
    int abase[MT];
#pragma unroll
    for (int mt = 0; mt < MT; ++mt)
        abase[mt] = ((row0 + 2*mt) * 18 + pxx) * PSTR + klane * 8;

    const bf16_t* Ab    = A + (size_t)b * PSZ * 2 * CINP;
    const bf16_t* wlane = Wp + (size_t)(ocBase + m) * 2 * CINP + klane * 8;

    for (int kc = 0; kc < NKC; ++kc) {
        __syncthreads();
        for (int i = tid; i < NCH; i += 256) {
            int pix = i >> 2, sub = i & 3;
            int pl = sub >> 1, half = sub & 1;
            int hy = pix / 18, hx = pix - hy * 18;
            const bf16_t* src = Ab + ((size_t)((y0 + hy) * PW + x0 + hx) * 2 + pl) * CINP
                                + kc * 16 + half * 8;
            *(bf16x8*)(s_a + pix * PSTR + pl * 16 + half * 8) = *(const bf16x8*)src;
        }
        __syncthreads();
        const bf16_t* wkc = wlane + kc * 16;
#pragma unroll
        for (int tap = 0; tap < 9; ++tap) {
            const int aoff = ((tap / 3) * 18 + (tap % 3)) * PSTR;
            const bf16_t* bpt = wkc + (size_t)tap * OCP * 2 * CINP;
            bf16x8 Bh[NT], Bl[NT];
#pragma unroll
            for (int nt = 0; nt < NT; ++nt) {
                Bh[nt] = *(const bf16x8*)(bpt + (size_t)(nt * 64) * CINP);
                Bl[nt] = *(const bf16x8*)(bpt + (size_t)(nt * 64) * CINP + CINP);
            }
#pragma unroll
            for (int mt = 0; mt < MT; ++mt) {
                bf16x8 Ah = *(const bf16x8*)(s_a + abase[mt] + aoff);
                bf16x8 Al = *(const bf16x8*)(s_a + abase[mt] + aoff + 16);
#pragma unroll
                for (int nt = 0; nt < NT; ++nt) {
                    acc[mt][nt] = __builtin_amdgcn_mfma_f32_32x32x16_bf16(Ah, Bh[nt], acc[mt][nt], 0,0,0);
                    acc[mt][nt] = __builtin_amdgcn_mfma_f32_32x32x16_bf16(Al, Bh[nt], acc[mt][nt], 0,0,0);
                    acc[mt][nt] = __builtin_amdgcn_mfma_f32_32x32x16_bf16(Ah, Bl[nt], acc[mt][nt], 0,0,0);
                }
            }
        }
    }

#pragma unroll
    for (int nt = 0; nt < NT; ++nt) {
        const int oc = ocBase + nt * 32 + m;
        if (EPI == 1 && oc >= OC) continue;
        const float bv = bias[oc];
#pragma unroll
        for (int mt = 0; mt < MT; ++mt) {
#pragma unroll
            for (int r = 0; r < 16; ++r) {
                const int row = (r & 3) + 8 * (r >> 2) + 4 * klane;
                const int pyy = wv * 2 * MT + mt * 2 + (row >> 4);
                const int gy = y0 + pyy, gx = x0 + (row & 15);
                float v = acc[mt][nt][r] + bv;
                if (EPI == 0) {
                    v = lrelu_f(v);
                    bf16_t h, l; split_bf16(v, h, l);
                    bf16_t* o = (bf16_t*)outv;
                    size_t base = ((size_t)(b * PSZ + (gy + 1) * PW + (gx + 1))) * 128 + oc;
                    o[base]      = h;
                    o[base + 64] = l;
                } else {
                    float* o = (float*)outv;
                    if (oc < 288) {
                        const int fch = (oc & 1) ^ 1;
                        float fl = flow[(size_t)(b*2 + fch) * HWSZ + gy * WW + gx];
                        v = 10.0f * tanhf(v) + fl;
                    } else {
                        v = 1.0f / (1.0f + expf(-v));
                    }
                    o[((size_t)(b * 432 + oc) << 14) + gy * WW + gx] = v;
                }
            }
        }
    }
}

// ---------------------------------------------------------------------------
// dcn as gather-into-MFMA-fragments (unchanged).
// ---------------------------------------------------------------------------
__global__ __launch_bounds__(256, 2)
void dcn_mfma_k(const float* __restrict__ xT, const float* __restrict__ off4,
                const bf16_t* __restrict__ Bp, const float* __restrict__ bias,
                float* __restrict__ out)
{
    const int tid   = threadIdx.x;
    const int lane  = tid & 63;
    const int wv    = tid >> 6;
    const int klane = lane >> 5;
    const int m     = lane & 31;
    const int b     = blockIdx.z;
    const int tx0 = blockIdx.x * 16, ty0 = blockIdx.y * 8;
    const int py = ty0 + wv * 2 + (m >> 4);
    const int px = tx0 + (m & 15);
    const int pixoff = py * WW + px;

    const float* offb = off4 + (size_t)b * 432 * HWSZ;
    const float* xTb  = xT   + (size_t)b * HWSZ * 64;

    f32x16 acc[2];
#pragma unroll
    for (int nt = 0; nt < 2; ++nt)
#pragma unroll
        for (int r = 0; r < 16; ++r) acc[nt][r] = 0.0f;

    for (int dg = 0; dg < 16; ++dg) {
        bf16x8 Ah[3], Al[3];
#pragma unroll
        for (int ks = 0; ks < 3; ++ks) {
            float sv[8];
#pragma unroll
            for (int j = 0; j < 8; ++j) sv[j] = 0.0f;
#pragma unroll
            for (int tt = 0; tt < 2; ++tt) {
                const int tap = ks * 4 + klane * 2 + tt;
                if (tap < 9) {
                    const int ch = dg * 9 + tap;
                    float oy = offb[(size_t)(2*ch    ) * HWSZ + pixoff];
                    float ox = offb[(size_t)(2*ch + 1) * HWSZ + pixoff];
                    float mk = offb[(size_t)(288 + ch) * HWSZ + pixoff];
                    float ys = (float)py + (float)(tap / 3 - 1) + oy;
                    float xs = (float)px + (float)(tap % 3 - 1) + ox;
                    float y0f = floorf(ys), x0f = floorf(xs);
                    float wy = ys - y0f,    wx = xs - x0f;
                    int y0 = (int)y0f, x0i = (int)x0f;
                    int y1 = y0 + 1,   x1  = x0i + 1;
                    float fy0 = (y0  >= 0 && y0  < HH) ? 1.0f : 0.0f;
                    float fy1 = (y1  >= 0 && y1  < HH) ? 1.0f : 0.0f;
                    float fx0 = (x0i >= 0 && x0i < WW) ? 1.0f : 0.0f;
                    float fx1 = (x1  >= 0 && x1  < WW) ? 1.0f : 0.0f;
                    int yc0 = min(max(y0, 0), HH-1), yc1 = min(max(y1, 0), HH-1);
                    int xc0 = min(max(x0i,0), WW-1), xc1 = min(max(x1, 0), WW-1);
                    float w00 = (1.0f-wy)*(1.0f-wx)*fy0*fx0*mk;
                    float w01 = (1.0f-wy)*wx       *fy0*fx1*mk;
                    float w10 = wy       *(1.0f-wx)*fy1*fx0*mk;
                    float w11 = wy       *wx       *fy1*fx1*mk;
                    const float* p00 = xTb + ((size_t)(yc0*WW + xc0) * 64 + dg*4);
                    const float* p01 = xTb + ((size_t)(yc0*WW + xc1) * 64 + dg*4);
                    const float* p10 = xTb + ((size_t)(yc1*WW + xc0) * 64 + dg*4);
                    const float* p11 = xTb + ((size_t)(yc1*WW + xc1) * 64 + dg*4);
                    float4 c00 = *(const float4*)p00;
                    float4 c01 = *(const float4*)p01;
                    float4 c10 = *(const float4*)p10;
                    float4 c11 = *(const float4*)p11;
                    sv[tt*4+0] = c00.x*w00 + c01.x*w01 + c10.x*w10 + c11.x*w11;
                    sv[tt*4+1] = c00.y*w00 + c01.y*w01 + c10.y*w10 + c11.y*w11;
                    sv[tt*4+2] = c00.z*w00 + c01.z*w01 + c10.z*w10 + c11.z*w11;
                    sv[tt*4+3] = c00.w*w00 + c01.w*w01 + c10.w*w10 + c11.w*w11;
                }
            }
            bf16x8 h, l;
#pragma unroll
            for (int j = 0; j < 8; ++j) {
                bf16_t hh, ll; split_bf16(sv[j], hh, ll);
                h[j] = hh; l[j] = ll;
            }
            Ah[ks] = h; Al[ks] = l;
        }
        const bf16_t* bbase = Bp + (size_t)(dg * 3) * 64 * 2 * 16;
#pragma unroll
        for (int ks = 0; ks < 3; ++ks) {
#pragma unroll
            for (int nt = 0; nt < 2; ++nt) {
                const bf16_t* bp = bbase + ((size_t)(ks*64 + nt*32 + m) * 2) * 16 + klane*8;
                bf16x8 Bh = *(const bf16x8*)bp;
                bf16x8 Bl = *(const bf16x8*)(bp + 16);
                acc[nt] = __builtin_amdgcn_mfma_f32_32x32x16_bf16(Ah[ks], Bh, acc[nt], 0,0,0);
                acc[nt] = __builtin_amdgcn_mfma_f32_32x32x16_bf16(Al[ks], Bh, acc[nt], 0,0,0);
                acc[nt] = __builtin_amdgcn_mfma_f32_32x32x16_bf16(Ah[ks], Bl, acc[nt], 0,0,0);
            }
        }
    }

#pragma unroll
    for (int nt = 0; nt < 2; ++nt) {
        const int oc = nt * 32 + m;
        const float bv = bias[oc];
#pragma unroll
        for (int r = 0; r < 16; ++r) {
            const int row = (r & 3) + 8 * (r >> 2) + 4 * klane;
            const int gy = ty0 + wv * 2 + (row >> 4);
            const int gx = tx0 + (row & 15);
            out[((size_t)(b*64 + oc) << 14) + gy * WW + gx] = acc[nt][r] + bv;
        }
    }
}

// ---------------------------------------------------------------------------
// Workspace layout (total ~132.6 MB; 142 MiB limit inferred R5/R6):
//   [0, 113.2MB)  off4 region:  A0 @ +0 (43.3MB, dead after conv1),
//                               h2p @ +44.04MB (17.3MB, dead after conv3)
//   [113.2, 130.5MB)  h1p (xT aliases it after conv4)
//   [130.5, ...]      packed weights (wp1..wp4, Bp)
// ---------------------------------------------------------------------------
extern "C" void kernel_launch(void* const* d_in, const int* in_sizes, int n_in,
                              void* d_out, int out_size, void* d_ws, size_t ws_size,
                              hipStream_t stream)
{
    const float* x    = (const float*)d_in[0];
    const float* xfw  = (const float*)d_in[1];
    const float* xc   = (const float*)d_in[2];
    const float* flow = (const float*)d_in[3];
    const float* w1 = (const float*)d_in[4];  const float* b1 = (const float*)d_in[5];
    const float* w2 = (const float*)d_in[6];  const float* b2 = (const float*)d_in[7];
    const float* w3 = (const float*)d_in[8];  const float* b3 = (const float*)d_in[9];
    const float* w4 = (const float*)d_in[10]; const float* b4 = (const float*)d_in[11];
    const float* dw = (const float*)d_in[12]; const float* db = (const float*)d_in[13];

    char* wsb = (char*)d_ws;
    const size_t off4_bytes = (size_t)BB * 432 * HWSZ * 4;      // 113,246,208
    float*  off4 = (float*)wsb;
    bf16_t* A0   = (bf16_t*)wsb;
    bf16_t* h2p  = (bf16_t*)(wsb + 44040192);
    char* p = wsb + off4_bytes;
    bf16_t* h1p = (bf16_t*)p;  float* xT = (float*)h1p;
                               p += (size_t)BB * PSZ * 2 * 64 * 2;
    bf16_t* wp1 = (bf16_t*)p;  p += (size_t)9 * 64  * 2 * 160 * 2;
    bf16_t* wp2 = (bf16_t*)p;  p += (size_t)9 * 64  * 2 * 64  * 2;
    bf16_t* wp3 = (bf16_t*)p;  p += (size_t)9 * 64  * 2 * 64  * 2;
    bf16_t* wp4 = (bf16_t*)p;  p += (size_t)9 * 512 * 2 * 64  * 2;   // OCP=512 (NT=4, z=4)
    bf16_t* Bp  = (bf16_t*)p;  p += (size_t)16 * 3 * 64 * 2 * 16 * 2;

    zero_border_k<<<(2064*16 + 255)/256, 256, 0, stream>>>(h1p, h2p);
    pack_w_k<<<(9*64*160  + 255)/256, 256, 0, stream>>>(w1, wp1, 64, 130, 64, 160);
    pack_w_k<<<(9*64*64   + 255)/256, 256, 0, stream>>>(w2, wp2, 64, 64, 64, 64);
    pack_w_k<<<(9*64*64   + 255)/256, 256, 0, stream>>>(w3, wp3, 64, 64, 64, 64);
    pack_w_k<<<(9*512*64  + 255)/256, 256, 0, stream>>>(w4, wp4, 432, 64, 512, 64);
    pack_dw_k<<<(16*48*64 + 255)/256, 256, 0, stream>>>(dw, Bp);
    pack_a0_k<<<(BB*PSZ*160 + 255)/256, 256, 0, stream>>>(xfw, xc, flow, A0);

    // conv chain: conv1-3 MT=1 NT=2 (OC=64); conv4 MT=2 NT=4 (128 oc/block, z=4)
    conv_mfma_k<160,1,2,0><<<dim3(128, BB, 1), 256, 0, stream>>>(A0,  wp1, b1, h1p, 64,  64,  nullptr);
    conv_mfma_k<64, 1,2,0><<<dim3(128, BB, 1), 256, 0, stream>>>(h1p, wp2, b2, h2p, 64,  64,  nullptr);
    conv_mfma_k<64, 1,2,0><<<dim3(128, BB, 1), 256, 0, stream>>>(h2p, wp3, b3, h1p, 64,  64,  nullptr);
    conv_mfma_k<64, 2,4,1><<<dim3(64, BB, 4), 256, 0, stream>>>(h1p, wp4, b4, off4, 512, 432, flow);
    // xT overwrites h1p (dead after conv4)
    pack_xt_k<<<BB * HWSZ / 64, 256, 0, stream>>>(x, xT);

    dcn_mfma_k<<<dim3(8, 16, BB), 256, 0, stream>>>(xT, off4, Bp, db, (float*)d_out);
}

// Round 8
// 563.237 us; speedup vs baseline: 1.2566x; 1.2566x over previous
//
#include <hip/hip_runtime.h>
#include <math.h>

#define HH 128
#define WW 128
#define BB 4
#define HWSZ (HH*WW)
#define PW 130          // padded image width/height
#define PSZ (PW*PW)     // 16900 padded pixels

typedef __bf16 bf16_t;
typedef bf16_t bf16x8 __attribute__((ext_vector_type(8)));
typedef float  f32x16 __attribute__((ext_vector_type(16)));

__device__ __forceinline__ void split_bf16(float v, bf16_t& h, bf16_t& l) {
    h = (bf16_t)v;
    l = (bf16_t)(v - (float)h);
}
__device__ __forceinline__ float lrelu_f(float v) { return v >= 0.0f ? v : 0.1f * v; }

// ---------------------------------------------------------------------------
// pack A0 (PADDED): [xfw(64)|xc(64)|flow(2)|zeros(14)] -> [b][130x130][pl2][144]
// ---------------------------------------------------------------------------
__global__ __launch_bounds__(256)
void pack_a0_k(const float* __restrict__ xfw, const float* __restrict__ xc,
               const float* __restrict__ flow, bf16_t* __restrict__ a0)
{
    int idx = blockIdx.x * 256 + threadIdx.x;           // BB*PSZ*144
    if (idx >= BB * PSZ * 144) return;
    int c = idx % 144; int pixp = idx / 144;
    int b = pixp / PSZ; int p = pixp - b * PSZ;
    int yy = p / PW, xx = p - yy * PW;
    float v = 0.0f;
    if (yy >= 1 && yy <= HH && xx >= 1 && xx <= WW) {
        int pi = (yy - 1) * WW + (xx - 1);
        if (c < 64)       v = xfw[(size_t)(b*64 + c) * HWSZ + pi];
        else if (c < 128) v = xc [(size_t)(b*64 + c - 64) * HWSZ + pi];
        else if (c < 130) v = flow[(size_t)(b*2 + c - 128) * HWSZ + pi];
    }
    bf16_t h, l; split_bf16(v, h, l);
    size_t base = (size_t)pixp * 288 + c;
    a0[base]       = h;
    a0[base + 144] = l;
}

// ---------------------------------------------------------------------------
// zero 1-px borders of h1p/h2p (padded [b][130x130][pl2][64] bf16); runs
// every call (ws re-poisoned).
// ---------------------------------------------------------------------------
__global__ __launch_bounds__(256)
void zero_border_k(bf16_t* __restrict__ h1, bf16_t* __restrict__ h2)
{
    int idx = blockIdx.x * 256 + threadIdx.x;           // 2064*16 = 33024
    if (idx >= 2064 * 16) return;
    int chunk = idx & 15; int bp = idx >> 4;
    int b = bp / 516;     int rr = bp - b * 516;
    int yy, xx;
    if (rr < 130)      { yy = 0;        xx = rr; }
    else if (rr < 260) { yy = 129;      xx = rr - 130; }
    else if (rr < 388) { yy = rr - 259; xx = 0; }
    else               { yy = rr - 387; xx = 129; }
    size_t base = ((size_t)(b * PSZ + yy * PW + xx)) * 128 + chunk * 8;
    bf16x8 z = {(bf16_t)0.f,(bf16_t)0.f,(bf16_t)0.f,(bf16_t)0.f,
                (bf16_t)0.f,(bf16_t)0.f,(bf16_t)0.f,(bf16_t)0.f};
    *(bf16x8*)(h1 + base) = z;
    *(bf16x8*)(h2 + base) = z;
}

// ---------------------------------------------------------------------------
// pack conv weights: W[oc][cin][3][3] fp32 ->
//   Wp[ocg][kc][tap][pl][ks][oc64][8]  (bf16; per-block per-kc slice contiguous)
// idx enumeration == output address.
// ---------------------------------------------------------------------------
__global__ __launch_bounds__(256)
void pack_w_k(const float* __restrict__ w, bf16_t* __restrict__ wp,
              int OC, int CIN, int OCP, int CINP, int NKC)
{
    int idx = blockIdx.x * 256 + threadIdx.x;           // OCP*CINP*18
    if (idx >= OCP * CINP * 18) return;
    int j    = idx & 7;
    int oc64 = (idx >> 3) & 63;
    int ks   = (idx >> 9) & 1;
    int pl   = (idx >> 10) & 1;
    int t    = idx >> 11;
    int tap  = t % 9;
    int rest = t / 9;            // ocg*NKC + kc
    int kc   = rest % NKC;
    int ocg  = rest / NKC;
    int oc   = ocg * 64 + oc64;
    int cin  = kc * 16 + ks * 8 + j;
    float v = (oc < OC && cin < CIN) ? w[((size_t)oc * CIN + cin) * 9 + tap] : 0.0f;
    bf16_t h, l; split_bf16(v, h, l);
    wp[idx] = (pl == 0) ? h : l;
}

// ---------------------------------------------------------------------------
// pack dcn weights: dw[oc64][cin64][3][3] -> Bp[dg16][ks3][oc64][pl2][16] bf16
// ---------------------------------------------------------------------------
__global__ __launch_bounds__(256)
void pack_dw_k(const float* __restrict__ dw, bf16_t* __restrict__ Bp)
{
    int idx = blockIdx.x * 256 + threadIdx.x;
    if (idx >= 16 * 48 * 64) return;
    int oc = idx & 63; int rest = idx >> 6;
    int kk = rest % 48; int dg = rest / 48;
    int tap = kk >> 2, cg = kk & 3;
    int ks = kk >> 4,  kj = kk & 15;
    float v = (tap < 9) ? dw[((size_t)oc * 64 + dg*4 + cg) * 9 + tap] : 0.0f;
    bf16_t h, l; split_bf16(v, h, l);
    size_t base = (((size_t)(dg*3 + ks) * 64 + oc) * 2) * 16 + kj;
    Bp[base]      = h;
    Bp[base + 16] = l;
}

// ---------------------------------------------------------------------------
// transpose x NCHW fp32 -> xT NHWC fp32 [b][pix][64]
// ---------------------------------------------------------------------------
__global__ __launch_bounds__(256)
void pack_xt_k(const float* __restrict__ x, float* __restrict__ xT)
{
    __shared__ float s[64][65];
    const int tid = threadIdx.x;
    const int p0 = blockIdx.x * 64;
    const int b = p0 >> 14, pp = p0 & 16383;
    for (int i = tid; i < 4096; i += 256) {
        int c = i >> 6, p = i & 63;
        s[p][c] = x[((size_t)(b*64 + c) << 14) + pp + p];
    }
    __syncthreads();
    for (int i = tid; i < 4096; i += 256) {
        int p = i >> 6, c = i & 63;
        xT[((size_t)(b << 14) + pp + p) * 64 + c] = s[p][c];
    }
}

// ---------------------------------------------------------------------------
// MFMA implicit-GEMM 3x3 SAME conv, A AND B staged in LDS.
// NT=2 fixed (64 oc/block). Per tap: 8 LDS b128 reads feed 12 MFMAs
// (LDS ~96cyc vs MFMA 96cyc per CU — balanced). B slice (36.9KB/kc) staged
// once per block (was 4x redundant global reads per wave in R6/R7).
// B LDS layout [tap][pl][ks][oc64][8]: lane-stride 16B -> conflict-free.
// ---------------------------------------------------------------------------
template<int CINP, int MT, int EPI>
__global__ __launch_bounds__(256, (MT == 1 ? 3 : 2))
void conv_mfma_k(const bf16_t* __restrict__ A, const bf16_t* __restrict__ Wp,
                 const float* __restrict__ bias, void* __restrict__ outv,
                 int OC, const float* __restrict__ flow)
{
    constexpr int NKC   = CINP / 16;
    constexpr int PSTR  = 40;
    constexpr int PROWS = 8 * MT;
    constexpr int HALO  = (PROWS + 2) * 18;
    constexpr int NCH_A = HALO * 4;           // A 16B chunks per kc
    constexpr int NCH_B = 9 * 2 * 2 * 64;     // 2304 B 16B chunks per kc
    const int tid  = threadIdx.x;
    const int lane = tid & 63;
    const int wv   = tid >> 6;
    const int b     = blockIdx.y;
    const int patch = blockIdx.x;
    const int y0 = (patch >> 3) * PROWS;
    const int x0 = (patch & 7) * 16;
    const int ocBase = blockIdx.z * 64;

    __shared__ __align__(16) bf16_t s_a[HALO * PSTR];
    __shared__ __align__(16) bf16_t s_b[NCH_B * 8];

    f32x16 acc[MT][2];
#pragma unroll
    for (int mt = 0; mt < MT; ++mt)
#pragma unroll
        for (int nt = 0; nt < 2; ++nt)
#pragma unroll
            for (int r = 0; r < 16; ++r) acc[mt][nt][r] = 0.0f;

    const int m     = lane & 31;
    const int klane = lane >> 5;
    const int row0  = wv * 2 * MT + (m >> 4);
    const int pxx   = m & 15;
    int abase[MT];
#pragma unroll
    for (int mt = 0; mt < MT; ++mt)
        abase[mt] = ((row0 + 2*mt) * 18 + pxx) * PSTR + klane * 8;

    const bf16_t* Ab = A + (size_t)b * PSZ * 2 * CINP;

    for (int kc = 0; kc < NKC; ++kc) {
        __syncthreads();
        // stage A halo k-chunk
        for (int i = tid; i < NCH_A; i += 256) {
            int pix = i >> 2, sub = i & 3;
            int pl = sub >> 1, half = sub & 1;
            int hy = pix / 18, hx = pix - hy * 18;
            const bf16_t* src = Ab + ((size_t)((y0 + hy) * PW + x0 + hx) * 2 + pl) * CINP
                                + kc * 16 + half * 8;
            *(bf16x8*)(s_a + pix * PSTR + pl * 16 + half * 8) = *(const bf16x8*)src;
        }
        // stage B slice (contiguous copy, 36.9 KB)
        {
            const bf16_t* wsrc = Wp + ((size_t)(blockIdx.z * NKC + kc) * NCH_B) * 8;
            for (int i = tid; i < NCH_B; i += 256)
                *(bf16x8*)(s_b + i * 8) = *(const bf16x8*)(wsrc + i * 8);
        }
        __syncthreads();

#pragma unroll
        for (int tap = 0; tap < 9; ++tap) {
            const int aoff = ((tap / 3) * 18 + (tap % 3)) * PSTR;
            bf16x8 Bh[2], Bl[2];
#pragma unroll
            for (int nt = 0; nt < 2; ++nt) {
                Bh[nt] = *(const bf16x8*)(s_b + (((tap*2 + 0)*2 + klane)*64 + nt*32 + m)*8);
                Bl[nt] = *(const bf16x8*)(s_b + (((tap*2 + 1)*2 + klane)*64 + nt*32 + m)*8);
            }
#pragma unroll
            for (int mt = 0; mt < MT; ++mt) {
                bf16x8 Ah = *(const bf16x8*)(s_a + abase[mt] + aoff);
                bf16x8 Al = *(const bf16x8*)(s_a + abase[mt] + aoff + 16);
#pragma unroll
                for (int nt = 0; nt < 2; ++nt) {
                    acc[mt][nt] = __builtin_amdgcn_mfma_f32_32x32x16_bf16(Ah, Bh[nt], acc[mt][nt], 0,0,0);
                    acc[mt][nt] = __builtin_amdgcn_mfma_f32_32x32x16_bf16(Al, Bh[nt], acc[mt][nt], 0,0,0);
                    acc[mt][nt] = __builtin_amdgcn_mfma_f32_32x32x16_bf16(Ah, Bl[nt], acc[mt][nt], 0,0,0);
                }
            }
        }
    }

#pragma unroll
    for (int nt = 0; nt < 2; ++nt) {
        const int oc = ocBase + nt * 32 + m;
        if (EPI == 1 && oc >= OC) continue;
        const float bv = bias[oc];
#pragma unroll
        for (int mt = 0; mt < MT; ++mt) {
#pragma unroll
            for (int r = 0; r < 16; ++r) {
                const int row = (r & 3) + 8 * (r >> 2) + 4 * klane;
                const int pyy = wv * 2 * MT + mt * 2 + (row >> 4);
                const int gy = y0 + pyy, gx = x0 + (row & 15);
                float v = acc[mt][nt][r] + bv;
                if (EPI == 0) {
                    v = lrelu_f(v);
                    bf16_t h, l; split_bf16(v, h, l);
                    bf16_t* o = (bf16_t*)outv;
                    size_t base = ((size_t)(b * PSZ + (gy + 1) * PW + (gx + 1))) * 128 + oc;
                    o[base]      = h;
                    o[base + 64] = l;
                } else {
                    float* o = (float*)outv;
                    if (oc < 288) {
                        const int fch = (oc & 1) ^ 1;
                        float fl = flow[(size_t)(b*2 + fch) * HWSZ + gy * WW + gx];
                        v = 10.0f * tanhf(v) + fl;
                    } else {
                        v = 1.0f / (1.0f + expf(-v));
                    }
                    o[((size_t)(b * 432 + oc) << 14) + gy * WW + gx] = v;
                }
            }
        }
    }
}

// ---------------------------------------------------------------------------
// dcn as gather-into-MFMA-fragments (unchanged).
// ---------------------------------------------------------------------------
__global__ __launch_bounds__(256, 2)
void dcn_mfma_k(const float* __restrict__ xT, const float* __restrict__ off4,
                const bf16_t* __restrict__ Bp, const float* __restrict__ bias,
                float* __restrict__ out)
{
    const int tid   = threadIdx.x;
    const int lane  = tid & 63;
    const int wv    = tid >> 6;
    const int klane = lane >> 5;
    const int m     = lane & 31;
    const int b     = blockIdx.z;
    const int tx0 = blockIdx.x * 16, ty0 = blockIdx.y * 8;
    const int py = ty0 + wv * 2 + (m >> 4);
    const int px = tx0 + (m & 15);
    const int pixoff = py * WW + px;

    const float* offb = off4 + (size_t)b * 432 * HWSZ;
    const float* xTb  = xT   + (size_t)b * HWSZ * 64;

    f32x16 acc[2];
#pragma unroll
    for (int nt = 0; nt < 2; ++nt)
#pragma unroll
        for (int r = 0; r < 16; ++r) acc[nt][r] = 0.0f;

    for (int dg = 0; dg < 16; ++dg) {
        bf16x8 Ah[3], Al[3];
#pragma unroll
        for (int ks = 0; ks < 3; ++ks) {
            float sv[8];
#pragma unroll
            for (int j = 0; j < 8; ++j) sv[j] = 0.0f;
#pragma unroll
            for (int tt = 0; tt < 2; ++tt) {
                const int tap = ks * 4 + klane * 2 + tt;
                if (tap < 9) {
                    const int ch = dg * 9 + tap;
                    float oy = offb[(size_t)(2*ch    ) * HWSZ + pixoff];
                    float ox = offb[(size_t)(2*ch + 1) * HWSZ + pixoff];
                    float mk = offb[(size_t)(288 + ch) * HWSZ + pixoff];
                    float ys = (float)py + (float)(tap / 3 - 1) + oy;
                    float xs = (float)px + (float)(tap % 3 - 1) + ox;
                    float y0f = floorf(ys), x0f = floorf(xs);
                    float wy = ys - y0f,    wx = xs - x0f;
                    int y0 = (int)y0f, x0i = (int)x0f;
                    int y1 = y0 + 1,   x1  = x0i + 1;
                    float fy0 = (y0  >= 0 && y0  < HH) ? 1.0f : 0.0f;
                    float fy1 = (y1  >= 0 && y1  < HH) ? 1.0f : 0.0f;
                    float fx0 = (x0i >= 0 && x0i < WW) ? 1.0f : 0.0f;
                    float fx1 = (x1  >= 0 && x1  < WW) ? 1.0f : 0.0f;
                    int yc0 = min(max(y0, 0), HH-1), yc1 = min(max(y1, 0), HH-1);
                    int xc0 = min(max(x0i,0), WW-1), xc1 = min(max(x1, 0), WW-1);
                    float w00 = (1.0f-wy)*(1.0f-wx)*fy0*fx0*mk;
                    float w01 = (1.0f-wy)*wx       *fy0*fx1*mk;
                    float w10 = wy       *(1.0f-wx)*fy1*fx0*mk;
                    float w11 = wy       *wx       *fy1*fx1*mk;
                    const float* p00 = xTb + ((size_t)(yc0*WW + xc0) * 64 + dg*4);
                    const float* p01 = xTb + ((size_t)(yc0*WW + xc1) * 64 + dg*4);
                    const float* p10 = xTb + ((size_t)(yc1*WW + xc0) * 64 + dg*4);
                    const float* p11 = xTb + ((size_t)(yc1*WW + xc1) * 64 + dg*4);
                    float4 c00 = *(const float4*)p00;
                    float4 c01 = *(const float4*)p01;
                    float4 c10 = *(const float4*)p10;
                    float4 c11 = *(const float4*)p11;
                    sv[tt*4+0] = c00.x*w00 + c01.x*w01 + c10.x*w10 + c11.x*w11;
                    sv[tt*4+1] = c00.y*w00 + c01.y*w01 + c10.y*w10 + c11.y*w11;
                    sv[tt*4+2] = c00.z*w00 + c01.z*w01 + c10.z*w10 + c11.z*w11;
                    sv[tt*4+3] = c00.w*w00 + c01.w*w01 + c10.w*w10 + c11.w*w11;
                }
            }
            bf16x8 h, l;
#pragma unroll
            for (int j = 0; j < 8; ++j) {
                bf16_t hh, ll; split_bf16(sv[j], hh, ll);
                h[j] = hh; l[j] = ll;
            }
            Ah[ks] = h; Al[ks] = l;
        }
        const bf16_t* bbase = Bp + (size_t)(dg * 3) * 64 * 2 * 16;
#pragma unroll
        for (int ks = 0; ks < 3; ++ks) {
#pragma unroll
            for (int nt = 0; nt < 2; ++nt) {
                const bf16_t* bp = bbase + ((size_t)(ks*64 + nt*32 + m) * 2) * 16 + klane*8;
                bf16x8 Bh = *(const bf16x8*)bp;
                bf16x8 Bl = *(const bf16x8*)(bp + 16);
                acc[nt] = __builtin_amdgcn_mfma_f32_32x32x16_bf16(Ah[ks], Bh, acc[nt], 0,0,0);
                acc[nt] = __builtin_amdgcn_mfma_f32_32x32x16_bf16(Al[ks], Bh, acc[nt], 0,0,0);
                acc[nt] = __builtin_amdgcn_mfma_f32_32x32x16_bf16(Ah[ks], Bl, acc[nt], 0,0,0);
            }
        }
    }

#pragma unroll
    for (int nt = 0; nt < 2; ++nt) {
        const int oc = nt * 32 + m;
        const float bv = bias[oc];
#pragma unroll
        for (int r = 0; r < 16; ++r) {
            const int row = (r & 3) + 8 * (r >> 2) + 4 * klane;
            const int gy = ty0 + wv * 2 + (row >> 4);
            const int gx = tx0 + (row & 15);
            out[((size_t)(b*64 + oc) << 14) + gy * WW + gx] = acc[nt][r] + bv;
        }
    }
}

// ---------------------------------------------------------------------------
// Workspace: off4 region [0,113.2MB) holds A0 (38.9MB, dead after conv1) and
// h2p @+44.04MB (17.3MB, dead after conv3); h1p after (xT aliases it post-
// conv4); packed weights at the end. Total ~132.5 MB (R6-proven size range).
// ---------------------------------------------------------------------------
extern "C" void kernel_launch(void* const* d_in, const int* in_sizes, int n_in,
                              void* d_out, int out_size, void* d_ws, size_t ws_size,
                              hipStream_t stream)
{
    const float* x    = (const float*)d_in[0];
    const float* xfw  = (const float*)d_in[1];
    const float* xc   = (const float*)d_in[2];
    const float* flow = (const float*)d_in[3];
    const float* w1 = (const float*)d_in[4];  const float* b1 = (const float*)d_in[5];
    const float* w2 = (const float*)d_in[6];  const float* b2 = (const float*)d_in[7];
    const float* w3 = (const float*)d_in[8];  const float* b3 = (const float*)d_in[9];
    const float* w4 = (const float*)d_in[10]; const float* b4 = (const float*)d_in[11];
    const float* dw = (const float*)d_in[12]; const float* db = (const float*)d_in[13];

    char* wsb = (char*)d_ws;
    const size_t off4_bytes = (size_t)BB * 432 * HWSZ * 4;      // 113,246,208
    float*  off4 = (float*)wsb;
    bf16_t* A0   = (bf16_t*)wsb;                                // 38.9MB, dead after conv1
    bf16_t* h2p  = (bf16_t*)(wsb + 44040192);                   // 17.3MB, dead after conv3
    char* p = wsb + off4_bytes;
    bf16_t* h1p = (bf16_t*)p;  float* xT = (float*)h1p;         // xT aliases h1p post-conv4
                               p += (size_t)BB * PSZ * 2 * 64 * 2;
    bf16_t* wp1 = (bf16_t*)p;  p += (size_t)64  * 144 * 18 * 2;
    bf16_t* wp2 = (bf16_t*)p;  p += (size_t)64  * 64  * 18 * 2;
    bf16_t* wp3 = (bf16_t*)p;  p += (size_t)64  * 64  * 18 * 2;
    bf16_t* wp4 = (bf16_t*)p;  p += (size_t)448 * 64  * 18 * 2;
    bf16_t* Bp  = (bf16_t*)p;  p += (size_t)16 * 3 * 64 * 2 * 16 * 2;

    zero_border_k<<<(2064*16 + 255)/256, 256, 0, stream>>>(h1p, h2p);
    pack_w_k<<<(64*144*18 + 255)/256, 256, 0, stream>>>(w1, wp1, 64, 130, 64, 144, 9);
    pack_w_k<<<(64*64*18  + 255)/256, 256, 0, stream>>>(w2, wp2, 64, 64, 64, 64, 4);
    pack_w_k<<<(64*64*18  + 255)/256, 256, 0, stream>>>(w3, wp3, 64, 64, 64, 64, 4);
    pack_w_k<<<(448*64*18 + 255)/256, 256, 0, stream>>>(w4, wp4, 432, 64, 448, 64, 4);
    pack_dw_k<<<(16*48*64 + 255)/256, 256, 0, stream>>>(dw, Bp);
    pack_a0_k<<<(BB*PSZ*144 + 255)/256, 256, 0, stream>>>(xfw, xc, flow, A0);

    // conv chain: NT=2 (64 oc/block), B staged in LDS
    conv_mfma_k<144,1,0><<<dim3(128, BB, 1), 256, 0, stream>>>(A0,  wp1, b1, h1p, 64,  nullptr);
    conv_mfma_k<64, 1,0><<<dim3(128, BB, 1), 256, 0, stream>>>(h1p, wp2, b2, h2p, 64,  nullptr);
    conv_mfma_k<64, 1,0><<<dim3(128, BB, 1), 256, 0, stream>>>(h2p, wp3, b3, h1p, 64,  nullptr);
    conv_mfma_k<64, 2,1><<<dim3(64, BB, 7), 256, 0, stream>>>(h1p, wp4, b4, off4, 432, flow);
    // xT overwrites h1p (dead after conv4)
    pack_xt_k<<<BB * HWSZ / 64, 256, 0, stream>>>(x, xT);

    dcn_mfma_k<<<dim3(8, 16, BB), 256, 0, stream>>>(xT, off4, Bp, db, (float*)d_out);
}

// Round 9
// 540.800 us; speedup vs baseline: 1.3087x; 1.0415x over previous
//
#include <hip/hip_runtime.h>
#include <math.h>

#define HH 128
#define WW 128
#define BB 4
#define HWSZ (HH*WW)
#define PW 130          // padded image width/height
#define PSZ (PW*PW)     // 16900 padded pixels

typedef __bf16 bf16_t;
typedef bf16_t bf16x8 __attribute__((ext_vector_type(8)));
typedef float  f32x16 __attribute__((ext_vector_type(16)));

__device__ __forceinline__ void split_bf16(float v, bf16_t& h, bf16_t& l) {
    h = (bf16_t)v;
    l = (bf16_t)(v - (float)h);
}
__device__ __forceinline__ float lrelu_f(float v) { return v >= 0.0f ? v : 0.1f * v; }

// ---------------------------------------------------------------------------
// pack A0 (PADDED): [xfw(64)|xc(64)|flow(2)|zeros(14)] -> [b][130x130][pl2][144]
// ---------------------------------------------------------------------------
__global__ __launch_bounds__(256)
void pack_a0_k(const float* __restrict__ xfw, const float* __restrict__ xc,
               const float* __restrict__ flow, bf16_t* __restrict__ a0)
{
    int idx = blockIdx.x * 256 + threadIdx.x;           // BB*PSZ*144
    if (idx >= BB * PSZ * 144) return;
    int c = idx % 144; int pixp = idx / 144;
    int b = pixp / PSZ; int p = pixp - b * PSZ;
    int yy = p / PW, xx = p - yy * PW;
    float v = 0.0f;
    if (yy >= 1 && yy <= HH && xx >= 1 && xx <= WW) {
        int pi = (yy - 1) * WW + (xx - 1);
        if (c < 64)       v = xfw[(size_t)(b*64 + c) * HWSZ + pi];
        else if (c < 128) v = xc [(size_t)(b*64 + c - 64) * HWSZ + pi];
        else if (c < 130) v = flow[(size_t)(b*2 + c - 128) * HWSZ + pi];
    }
    bf16_t h, l; split_bf16(v, h, l);
    size_t base = (size_t)pixp * 288 + c;
    a0[base]       = h;
    a0[base + 144] = l;
}

// ---------------------------------------------------------------------------
// zero 1-px borders of h1p/h2p (padded [b][130x130][pl2][64] bf16); runs
// every call (ws re-poisoned).
// ---------------------------------------------------------------------------
__global__ __launch_bounds__(256)
void zero_border_k(bf16_t* __restrict__ h1, bf16_t* __restrict__ h2)
{
    int idx = blockIdx.x * 256 + threadIdx.x;           // 2064*16 = 33024
    if (idx >= 2064 * 16) return;
    int chunk = idx & 15; int bp = idx >> 4;
    int b = bp / 516;     int rr = bp - b * 516;
    int yy, xx;
    if (rr < 130)      { yy = 0;        xx = rr; }
    else if (rr < 260) { yy = 129;      xx = rr - 130; }
    else if (rr < 388) { yy = rr - 259; xx = 0; }
    else               { yy = rr - 387; xx = 129; }
    size_t base = ((size_t)(b * PSZ + yy * PW + xx)) * 128 + chunk * 8;
    bf16x8 z = {(bf16_t)0.f,(bf16_t)0.f,(bf16_t)0.f,(bf16_t)0.f,
                (bf16_t)0.f,(bf16_t)0.f,(bf16_t)0.f,(bf16_t)0.f};
    *(bf16x8*)(h1 + base) = z;
    *(bf16x8*)(h2 + base) = z;
}

// ---------------------------------------------------------------------------
// pack conv weights: W[oc][cin][3][3] fp32 ->
//   Wp[ocg][kc][tap][pl][ks][oc64][8]  (bf16; per-block per-kc slice contiguous)
// ---------------------------------------------------------------------------
__global__ __launch_bounds__(256)
void pack_w_k(const float* __restrict__ w, bf16_t* __restrict__ wp,
              int OC, int CIN, int OCP, int CINP, int NKC)
{
    int idx = blockIdx.x * 256 + threadIdx.x;           // OCP*CINP*18
    if (idx >= OCP * CINP * 18) return;
    int j    = idx & 7;
    int oc64 = (idx >> 3) & 63;
    int ks   = (idx >> 9) & 1;
    int pl   = (idx >> 10) & 1;
    int t    = idx >> 11;
    int tap  = t % 9;
    int rest = t / 9;            // ocg*NKC + kc
    int kc   = rest % NKC;
    int ocg  = rest / NKC;
    int oc   = ocg * 64 + oc64;
    int cin  = kc * 16 + ks * 8 + j;
    float v = (oc < OC && cin < CIN) ? w[((size_t)oc * CIN + cin) * 9 + tap] : 0.0f;
    bf16_t h, l; split_bf16(v, h, l);
    wp[idx] = (pl == 0) ? h : l;
}

// ---------------------------------------------------------------------------
// pack dcn weights: dw[oc64][cin64][3][3] -> Bp[dg16][ks3][oc64][pl2][16] bf16
// ---------------------------------------------------------------------------
__global__ __launch_bounds__(256)
void pack_dw_k(const float* __restrict__ dw, bf16_t* __restrict__ Bp)
{
    int idx = blockIdx.x * 256 + threadIdx.x;
    if (idx >= 16 * 48 * 64) return;
    int oc = idx & 63; int rest = idx >> 6;
    int kk = rest % 48; int dg = rest / 48;
    int tap = kk >> 2, cg = kk & 3;
    int ks = kk >> 4,  kj = kk & 15;
    float v = (tap < 9) ? dw[((size_t)oc * 64 + dg*4 + cg) * 9 + tap] : 0.0f;
    bf16_t h, l; split_bf16(v, h, l);
    size_t base = (((size_t)(dg*3 + ks) * 64 + oc) * 2) * 16 + kj;
    Bp[base]      = h;
    Bp[base + 16] = l;
}

// ---------------------------------------------------------------------------
// transpose x NCHW fp32 -> xT NHWC fp32 [b][pix][64]
// ---------------------------------------------------------------------------
__global__ __launch_bounds__(256)
void pack_xt_k(const float* __restrict__ x, float* __restrict__ xT)
{
    __shared__ float s[64][65];
    const int tid = threadIdx.x;
    const int p0 = blockIdx.x * 64;
    const int b = p0 >> 14, pp = p0 & 16383;
    for (int i = tid; i < 4096; i += 256) {
        int c = i >> 6, p = i & 63;
        s[p][c] = x[((size_t)(b*64 + c) << 14) + pp + p];
    }
    __syncthreads();
    for (int i = tid; i < 4096; i += 256) {
        int p = i >> 6, c = i & 63;
        xT[((size_t)(b << 14) + pp + p) * 64 + c] = s[p][c];
    }
}

// ---------------------------------------------------------------------------
// MFMA implicit-GEMM 3x3 SAME conv, A AND B staged in LDS.
// B staged ASYNC via global_load_lds width=16 (lane-contiguous layout),
// issued first so B fetch latency overlaps manual A staging.
// ---------------------------------------------------------------------------
template<int CINP, int MT, int EPI>
__global__ __launch_bounds__(256, (MT == 1 ? 3 : 2))
void conv_mfma_k(const bf16_t* __restrict__ A, const bf16_t* __restrict__ Wp,
                 const float* __restrict__ bias, void* __restrict__ outv,
                 int OC, const float* __restrict__ flow)
{
    constexpr int NKC   = CINP / 16;
    constexpr int PSTR  = 40;
    constexpr int PROWS = 8 * MT;
    constexpr int HALO  = (PROWS + 2) * 18;
    constexpr int NCH_A = HALO * 4;           // A 16B chunks per kc
    constexpr int NCH_B = 9 * 2 * 2 * 64;     // 2304 B 16B chunks per kc
    const int tid  = threadIdx.x;
    const int lane = tid & 63;
    const int wv   = tid >> 6;
    const int b     = blockIdx.y;
    const int patch = blockIdx.x;
    const int y0 = (patch >> 3) * PROWS;
    const int x0 = (patch & 7) * 16;
    const int ocBase = blockIdx.z * 64;

    __shared__ __align__(16) bf16_t s_a[HALO * PSTR];
    __shared__ __align__(16) bf16_t s_b[NCH_B * 8];

    f32x16 acc[MT][2];
#pragma unroll
    for (int mt = 0; mt < MT; ++mt)
#pragma unroll
        for (int nt = 0; nt < 2; ++nt)
#pragma unroll
            for (int r = 0; r < 16; ++r) acc[mt][nt][r] = 0.0f;

    const int m     = lane & 31;
    const int klane = lane >> 5;
    const int row0  = wv * 2 * MT + (m >> 4);
    const int pxx   = m & 15;
    int abase[MT];
#pragma unroll
    for (int mt = 0; mt < MT; ++mt)
        abase[mt] = ((row0 + 2*mt) * 18 + pxx) * PSTR + klane * 8;

    const bf16_t* Ab = A + (size_t)b * PSZ * 2 * CINP;

    for (int kc = 0; kc < NKC; ++kc) {
        __syncthreads();
        // stage B slice ASYNC (global->LDS DMA, no VGPR round-trip).
        // chunk i lands at s_b + i*16B: wave-uniform base + lane*16 — the
        // exact pattern global_load_lds supports.
        {
            const bf16_t* wsrc = Wp + ((size_t)(blockIdx.z * NKC + kc) * NCH_B) * 8;
#pragma unroll
            for (int i = tid; i < NCH_B; i += 256)
                __builtin_amdgcn_global_load_lds(
                    (const __attribute__((address_space(1))) void*)(wsrc + i * 8),
                    (__attribute__((address_space(3))) void*)(s_b + i * 8),
                    16, 0, 0);
        }
        // stage A halo k-chunk (manual: padded layout, overlaps B DMA)
        for (int i = tid; i < NCH_A; i += 256) {
            int pix = i >> 2, sub = i & 3;
            int pl = sub >> 1, half = sub & 1;
            int hy = pix / 18, hx = pix - hy * 18;
            const bf16_t* src = Ab + ((size_t)((y0 + hy) * PW + x0 + hx) * 2 + pl) * CINP
                                + kc * 16 + half * 8;
            *(bf16x8*)(s_a + pix * PSTR + pl * 16 + half * 8) = *(const bf16x8*)src;
        }
        __syncthreads();

#pragma unroll
        for (int tap = 0; tap < 9; ++tap) {
            const int aoff = ((tap / 3) * 18 + (tap % 3)) * PSTR;
            bf16x8 Bh[2], Bl[2];
#pragma unroll
            for (int nt = 0; nt < 2; ++nt) {
                Bh[nt] = *(const bf16x8*)(s_b + (((tap*2 + 0)*2 + klane)*64 + nt*32 + m)*8);
                Bl[nt] = *(const bf16x8*)(s_b + (((tap*2 + 1)*2 + klane)*64 + nt*32 + m)*8);
            }
#pragma unroll
            for (int mt = 0; mt < MT; ++mt) {
                bf16x8 Ah = *(const bf16x8*)(s_a + abase[mt] + aoff);
                bf16x8 Al = *(const bf16x8*)(s_a + abase[mt] + aoff + 16);
#pragma unroll
                for (int nt = 0; nt < 2; ++nt) {
                    acc[mt][nt] = __builtin_amdgcn_mfma_f32_32x32x16_bf16(Ah, Bh[nt], acc[mt][nt], 0,0,0);
                    acc[mt][nt] = __builtin_amdgcn_mfma_f32_32x32x16_bf16(Al, Bh[nt], acc[mt][nt], 0,0,0);
                    acc[mt][nt] = __builtin_amdgcn_mfma_f32_32x32x16_bf16(Ah, Bl[nt], acc[mt][nt], 0,0,0);
                }
            }
        }
    }

#pragma unroll
    for (int nt = 0; nt < 2; ++nt) {
        const int oc = ocBase + nt * 32 + m;
        if (EPI == 1 && oc >= OC) continue;
        const float bv = bias[oc];
#pragma unroll
        for (int mt = 0; mt < MT; ++mt) {
#pragma unroll
            for (int r = 0; r < 16; ++r) {
                const int row = (r & 3) + 8 * (r >> 2) + 4 * klane;
                const int pyy = wv * 2 * MT + mt * 2 + (row >> 4);
                const int gy = y0 + pyy, gx = x0 + (row & 15);
                float v = acc[mt][nt][r] + bv;
                if (EPI == 0) {
                    v = lrelu_f(v);
                    bf16_t h, l; split_bf16(v, h, l);
                    bf16_t* o = (bf16_t*)outv;
                    size_t base = ((size_t)(b * PSZ + (gy + 1) * PW + (gx + 1))) * 128 + oc;
                    o[base]      = h;
                    o[base + 64] = l;
                } else {
                    float* o = (float*)outv;
                    if (oc < 288) {
                        const int fch = (oc & 1) ^ 1;
                        float fl = flow[(size_t)(b*2 + fch) * HWSZ + gy * WW + gx];
                        v = 10.0f * tanhf(v) + fl;
                    } else {
                        v = 1.0f / (1.0f + expf(-v));
                    }
                    o[((size_t)(b * 432 + oc) << 14) + gy * WW + gx] = v;
                }
            }
        }
    }
}

// ---------------------------------------------------------------------------
// dcn as gather-into-MFMA-fragments (unchanged).
// ---------------------------------------------------------------------------
__global__ __launch_bounds__(256, 2)
void dcn_mfma_k(const float* __restrict__ xT, const float* __restrict__ off4,
                const bf16_t* __restrict__ Bp, const float* __restrict__ bias,
                float* __restrict__ out)
{
    const int tid   = threadIdx.x;
    const int lane  = tid & 63;
    const int wv    = tid >> 6;
    const int klane = lane >> 5;
    const int m     = lane & 31;
    const int b     = blockIdx.z;
    const int tx0 = blockIdx.x * 16, ty0 = blockIdx.y * 8;
    const int py = ty0 + wv * 2 + (m >> 4);
    const int px = tx0 + (m & 15);
    const int pixoff = py * WW + px;

    const float* offb = off4 + (size_t)b * 432 * HWSZ;
    const float* xTb  = xT   + (size_t)b * HWSZ * 64;

    f32x16 acc[2];
#pragma unroll
    for (int nt = 0; nt < 2; ++nt)
#pragma unroll
        for (int r = 0; r < 16; ++r) acc[nt][r] = 0.0f;

    for (int dg = 0; dg < 16; ++dg) {
        bf16x8 Ah[3], Al[3];
#pragma unroll
        for (int ks = 0; ks < 3; ++ks) {
            float sv[8];
#pragma unroll
            for (int j = 0; j < 8; ++j) sv[j] = 0.0f;
#pragma unroll
            for (int tt = 0; tt < 2; ++tt) {
                const int tap = ks * 4 + klane * 2 + tt;
                if (tap < 9) {
                    const int ch = dg * 9 + tap;
                    float oy = offb[(size_t)(2*ch    ) * HWSZ + pixoff];
                    float ox = offb[(size_t)(2*ch + 1) * HWSZ + pixoff];
                    float mk = offb[(size_t)(288 + ch) * HWSZ + pixoff];
                    float ys = (float)py + (float)(tap / 3 - 1) + oy;
                    float xs = (float)px + (float)(tap % 3 - 1) + ox;
                    float y0f = floorf(ys), x0f = floorf(xs);
                    float wy = ys - y0f,    wx = xs - x0f;
                    int y0 = (int)y0f, x0i = (int)x0f;
                    int y1 = y0 + 1,   x1  = x0i + 1;
                    float fy0 = (y0  >= 0 && y0  < HH) ? 1.0f : 0.0f;
                    float fy1 = (y1  >= 0 && y1  < HH) ? 1.0f : 0.0f;
                    float fx0 = (x0i >= 0 && x0i < WW) ? 1.0f : 0.0f;
                    float fx1 = (x1  >= 0 && x1  < WW) ? 1.0f : 0.0f;
                    int yc0 = min(max(y0, 0), HH-1), yc1 = min(max(y1, 0), HH-1);
                    int xc0 = min(max(x0i,0), WW-1), xc1 = min(max(x1, 0), WW-1);
                    float w00 = (1.0f-wy)*(1.0f-wx)*fy0*fx0*mk;
                    float w01 = (1.0f-wy)*wx       *fy0*fx1*mk;
                    float w10 = wy       *(1.0f-wx)*fy1*fx0*mk;
                    float w11 = wy       *wx       *fy1*fx1*mk;
                    const float* p00 = xTb + ((size_t)(yc0*WW + xc0) * 64 + dg*4);
                    const float* p01 = xTb + ((size_t)(yc0*WW + xc1) * 64 + dg*4);
                    const float* p10 = xTb + ((size_t)(yc1*WW + xc0) * 64 + dg*4);
                    const float* p11 = xTb + ((size_t)(yc1*WW + xc1) * 64 + dg*4);
                    float4 c00 = *(const float4*)p00;
                    float4 c01 = *(const float4*)p01;
                    float4 c10 = *(const float4*)p10;
                    float4 c11 = *(const float4*)p11;
                    sv[tt*4+0] = c00.x*w00 + c01.x*w01 + c10.x*w10 + c11.x*w11;
                    sv[tt*4+1] = c00.y*w00 + c01.y*w01 + c10.y*w10 + c11.y*w11;
                    sv[tt*4+2] = c00.z*w00 + c01.z*w01 + c10.z*w10 + c11.z*w11;
                    sv[tt*4+3] = c00.w*w00 + c01.w*w01 + c10.w*w10 + c11.w*w11;
                }
            }
            bf16x8 h, l;
#pragma unroll
            for (int j = 0; j < 8; ++j) {
                bf16_t hh, ll; split_bf16(sv[j], hh, ll);
                h[j] = hh; l[j] = ll;
            }
            Ah[ks] = h; Al[ks] = l;
        }
        const bf16_t* bbase = Bp + (size_t)(dg * 3) * 64 * 2 * 16;
#pragma unroll
        for (int ks = 0; ks < 3; ++ks) {
#pragma unroll
            for (int nt = 0; nt < 2; ++nt) {
                const bf16_t* bp = bbase + ((size_t)(ks*64 + nt*32 + m) * 2) * 16 + klane*8;
                bf16x8 Bh = *(const bf16x8*)bp;
                bf16x8 Bl = *(const bf16x8*)(bp + 16);
                acc[nt] = __builtin_amdgcn_mfma_f32_32x32x16_bf16(Ah[ks], Bh, acc[nt], 0,0,0);
                acc[nt] = __builtin_amdgcn_mfma_f32_32x32x16_bf16(Al[ks], Bh, acc[nt], 0,0,0);
                acc[nt] = __builtin_amdgcn_mfma_f32_32x32x16_bf16(Ah[ks], Bl, acc[nt], 0,0,0);
            }
        }
    }

#pragma unroll
    for (int nt = 0; nt < 2; ++nt) {
        const int oc = nt * 32 + m;
        const float bv = bias[oc];
#pragma unroll
        for (int r = 0; r < 16; ++r) {
            const int row = (r & 3) + 8 * (r >> 2) + 4 * klane;
            const int gy = ty0 + wv * 2 + (row >> 4);
            const int gx = tx0 + (row & 15);
            out[((size_t)(b*64 + oc) << 14) + gy * WW + gx] = acc[nt][r] + bv;
        }
    }
}

// ---------------------------------------------------------------------------
// Workspace: off4 region [0,113.2MB) holds A0 (38.9MB, dead after conv1) and
// h2p @+44.04MB (17.3MB, dead after conv3); h1p after (xT aliases it post-
// conv4); packed weights at the end. Total ~132.5 MB (R6/R8-proven size).
// ---------------------------------------------------------------------------
extern "C" void kernel_launch(void* const* d_in, const int* in_sizes, int n_in,
                              void* d_out, int out_size, void* d_ws, size_t ws_size,
                              hipStream_t stream)
{
    const float* x    = (const float*)d_in[0];
    const float* xfw  = (const float*)d_in[1];
    const float* xc   = (const float*)d_in[2];
    const float* flow = (const float*)d_in[3];
    const float* w1 = (const float*)d_in[4];  const float* b1 = (const float*)d_in[5];
    const float* w2 = (const float*)d_in[6];  const float* b2 = (const float*)d_in[7];
    const float* w3 = (const float*)d_in[8];  const float* b3 = (const float*)d_in[9];
    const float* w4 = (const float*)d_in[10]; const float* b4 = (const float*)d_in[11];
    const float* dw = (const float*)d_in[12]; const float* db = (const float*)d_in[13];

    char* wsb = (char*)d_ws;
    const size_t off4_bytes = (size_t)BB * 432 * HWSZ * 4;      // 113,246,208
    float*  off4 = (float*)wsb;
    bf16_t* A0   = (bf16_t*)wsb;                                // dead after conv1
    bf16_t* h2p  = (bf16_t*)(wsb + 44040192);                   // dead after conv3
    char* p = wsb + off4_bytes;
    bf16_t* h1p = (bf16_t*)p;  float* xT = (float*)h1p;         // xT aliases h1p post-conv4
                               p += (size_t)BB * PSZ * 2 * 64 * 2;
    bf16_t* wp1 = (bf16_t*)p;  p += (size_t)64  * 144 * 18 * 2;
    bf16_t* wp2 = (bf16_t*)p;  p += (size_t)64  * 64  * 18 * 2;
    bf16_t* wp3 = (bf16_t*)p;  p += (size_t)64  * 64  * 18 * 2;
    bf16_t* wp4 = (bf16_t*)p;  p += (size_t)448 * 64  * 18 * 2;
    bf16_t* Bp  = (bf16_t*)p;  p += (size_t)16 * 3 * 64 * 2 * 16 * 2;

    zero_border_k<<<(2064*16 + 255)/256, 256, 0, stream>>>(h1p, h2p);
    pack_w_k<<<(64*144*18 + 255)/256, 256, 0, stream>>>(w1, wp1, 64, 130, 64, 144, 9);
    pack_w_k<<<(64*64*18  + 255)/256, 256, 0, stream>>>(w2, wp2, 64, 64, 64, 64, 4);
    pack_w_k<<<(64*64*18  + 255)/256, 256, 0, stream>>>(w3, wp3, 64, 64, 64, 64, 4);
    pack_w_k<<<(448*64*18 + 255)/256, 256, 0, stream>>>(w4, wp4, 432, 64, 448, 64, 4);
    pack_dw_k<<<(16*48*64 + 255)/256, 256, 0, stream>>>(dw, Bp);
    pack_a0_k<<<(BB*PSZ*144 + 255)/256, 256, 0, stream>>>(xfw, xc, flow, A0);

    // conv chain: NT=2 (64 oc/block), B staged async in LDS
    conv_mfma_k<144,1,0><<<dim3(128, BB, 1), 256, 0, stream>>>(A0,  wp1, b1, h1p, 64,  nullptr);
    conv_mfma_k<64, 1,0><<<dim3(128, BB, 1), 256, 0, stream>>>(h1p, wp2, b2, h2p, 64,  nullptr);
    conv_mfma_k<64, 1,0><<<dim3(128, BB, 1), 256, 0, stream>>>(h2p, wp3, b3, h1p, 64,  nullptr);
    conv_mfma_k<64, 2,1><<<dim3(64, BB, 7), 256, 0, stream>>>(h1p, wp4, b4, off4, 432, flow);
    // xT overwrites h1p (dead after conv4)
    pack_xt_k<<<BB * HWSZ / 64, 256, 0, stream>>>(x, xT);

    dcn_mfma_k<<<dim3(8, 16, BB), 256, 0, stream>>>(xT, off4, Bp, db, (float*)d_out);
}

// Round 10
// 523.608 us; speedup vs baseline: 1.3517x; 1.0328x over previous
//
#include <hip/hip_runtime.h>
#include <hip/hip_fp16.h>
#include <math.h>

#define HH 128
#define WW 128
#define BB 4
#define HWSZ (HH*WW)
#define PW 130          // padded image width/height
#define PSZ (PW*PW)     // 16900 padded pixels

typedef __bf16 bf16_t;
typedef bf16_t bf16x8 __attribute__((ext_vector_type(8)));
typedef float  f32x16 __attribute__((ext_vector_type(16)));

__device__ __forceinline__ void split_bf16(float v, bf16_t& h, bf16_t& l) {
    h = (bf16_t)v;
    l = (bf16_t)(v - (float)h);
}
__device__ __forceinline__ float lrelu_f(float v) { return v >= 0.0f ? v : 0.1f * v; }

// ---------------------------------------------------------------------------
// pack A0 via LDS transpose (old version read NCHW uncoalesced).
// Each block: 64 padded pixels x 144 ch. Load lanes = consecutive px per ch
// (coalesced within row segments); store lanes = consecutive ch (coalesced).
// ---------------------------------------------------------------------------
__global__ __launch_bounds__(256)
void pack_a0_k(const float* __restrict__ xfw, const float* __restrict__ xc,
               const float* __restrict__ flow, bf16_t* __restrict__ a0)
{
    __shared__ float s[64][145];
    const int tid = threadIdx.x;
    const int p0 = blockIdx.x * 64;                     // global padded pixel base
    for (int i = tid; i < 64 * 144; i += 256) {
        int c = i >> 6, px = i & 63;
        int pp = p0 + px;
        float v = 0.0f;
        if (pp < BB * PSZ) {
            int b = pp / PSZ; int p = pp - b * PSZ;
            int yy = p / PW, xx = p - yy * PW;
            if (yy >= 1 && yy <= HH && xx >= 1 && xx <= WW) {
                int pi = (yy - 1) * WW + (xx - 1);
                if (c < 64)       v = xfw[(size_t)(b*64 + c) * HWSZ + pi];
                else if (c < 128) v = xc [(size_t)(b*64 + c - 64) * HWSZ + pi];
                else if (c < 130) v = flow[(size_t)(b*2 + c - 128) * HWSZ + pi];
            }
        }
        s[px][c] = v;
    }
    __syncthreads();
    for (int i = tid; i < 64 * 144; i += 256) {
        int px = i / 144, c = i - px * 144;
        int pp = p0 + px;
        if (pp < BB * PSZ) {
            bf16_t h, l; split_bf16(s[px][c], h, l);
            size_t base = (size_t)pp * 288 + c;
            a0[base]       = h;
            a0[base + 144] = l;
        }
    }
}

// ---------------------------------------------------------------------------
// zero 1-px borders of ONE padded feature buffer [b][130x130][pl2][64] bf16.
// (h2p aliases A0 now, so its border zeroing must run AFTER conv1.)
// ---------------------------------------------------------------------------
__global__ __launch_bounds__(256)
void zero_border_k(bf16_t* __restrict__ hbuf)
{
    int idx = blockIdx.x * 256 + threadIdx.x;           // 2064*16 = 33024
    if (idx >= 2064 * 16) return;
    int chunk = idx & 15; int bp = idx >> 4;
    int b = bp / 516;     int rr = bp - b * 516;
    int yy, xx;
    if (rr < 130)      { yy = 0;        xx = rr; }
    else if (rr < 260) { yy = 129;      xx = rr - 130; }
    else if (rr < 388) { yy = rr - 259; xx = 0; }
    else               { yy = rr - 387; xx = 129; }
    size_t base = ((size_t)(b * PSZ + yy * PW + xx)) * 128 + chunk * 8;
    bf16x8 z = {(bf16_t)0.f,(bf16_t)0.f,(bf16_t)0.f,(bf16_t)0.f,
                (bf16_t)0.f,(bf16_t)0.f,(bf16_t)0.f,(bf16_t)0.f};
    *(bf16x8*)(hbuf + base) = z;
}

// ---------------------------------------------------------------------------
// pack conv weights: W[oc][cin][3][3] fp32 ->
//   Wp[ocg][kc][tap][pl][ks][oc64][8]  (bf16; per-block per-kc slice contiguous)
// ---------------------------------------------------------------------------
__global__ __launch_bounds__(256)
void pack_w_k(const float* __restrict__ w, bf16_t* __restrict__ wp,
              int OC, int CIN, int OCP, int CINP, int NKC)
{
    int idx = blockIdx.x * 256 + threadIdx.x;           // OCP*CINP*18
    if (idx >= OCP * CINP * 18) return;
    int j    = idx & 7;
    int oc64 = (idx >> 3) & 63;
    int ks   = (idx >> 9) & 1;
    int pl   = (idx >> 10) & 1;
    int t    = idx >> 11;
    int tap  = t % 9;
    int rest = t / 9;            // ocg*NKC + kc
    int kc   = rest % NKC;
    int ocg  = rest / NKC;
    int oc   = ocg * 64 + oc64;
    int cin  = kc * 16 + ks * 8 + j;
    float v = (oc < OC && cin < CIN) ? w[((size_t)oc * CIN + cin) * 9 + tap] : 0.0f;
    bf16_t h, l; split_bf16(v, h, l);
    wp[idx] = (pl == 0) ? h : l;
}

// ---------------------------------------------------------------------------
// pack dcn weights: dw[oc64][cin64][3][3] -> Bp[dg16][ks3][oc64][pl2][16] bf16
// ---------------------------------------------------------------------------
__global__ __launch_bounds__(256)
void pack_dw_k(const float* __restrict__ dw, bf16_t* __restrict__ Bp)
{
    int idx = blockIdx.x * 256 + threadIdx.x;
    if (idx >= 16 * 48 * 64) return;
    int oc = idx & 63; int rest = idx >> 6;
    int kk = rest % 48; int dg = rest / 48;
    int tap = kk >> 2, cg = kk & 3;
    int ks = kk >> 4,  kj = kk & 15;
    float v = (tap < 9) ? dw[((size_t)oc * 64 + dg*4 + cg) * 9 + tap] : 0.0f;
    bf16_t h, l; split_bf16(v, h, l);
    size_t base = (((size_t)(dg*3 + ks) * 64 + oc) * 2) * 16 + kj;
    Bp[base]      = h;
    Bp[base + 16] = l;
}

// ---------------------------------------------------------------------------
// transpose x NCHW fp32 -> xT NHWC fp32 [b][pix][64]
// ---------------------------------------------------------------------------
__global__ __launch_bounds__(256)
void pack_xt_k(const float* __restrict__ x, float* __restrict__ xT)
{
    __shared__ float s[64][65];
    const int tid = threadIdx.x;
    const int p0 = blockIdx.x * 64;
    const int b = p0 >> 14, pp = p0 & 16383;
    for (int i = tid; i < 4096; i += 256) {
        int c = i >> 6, p = i & 63;
        s[p][c] = x[((size_t)(b*64 + c) << 14) + pp + p];
    }
    __syncthreads();
    for (int i = tid; i < 4096; i += 256) {
        int p = i >> 6, c = i & 63;
        xT[((size_t)(b << 14) + pp + p) * 64 + c] = s[p][c];
    }
}

// ---------------------------------------------------------------------------
// MFMA implicit-GEMM 3x3 SAME conv, A AND B staged in LDS (B async DMA).
// EPI 1 (conv4) writes fp16 off4: offsets |v|<=20 -> fp16 abs err <=0.008 px,
// propagated through bilinear sampling ~0.002 RMS on the final output (under
// the 3.4e-2 budget). conv4 runs MT=1 -> 51.3KB LDS -> 3 blocks/CU.
// ---------------------------------------------------------------------------
template<int CINP, int MT, int EPI>
__global__ __launch_bounds__(256, (MT == 1 ? 3 : 2))
void conv_mfma_k(const bf16_t* __restrict__ A, const bf16_t* __restrict__ Wp,
                 const float* __restrict__ bias, void* __restrict__ outv,
                 int OC, const float* __restrict__ flow)
{
    constexpr int NKC   = CINP / 16;
    constexpr int PSTR  = 40;
    constexpr int PROWS = 8 * MT;
    constexpr int HALO  = (PROWS + 2) * 18;
    constexpr int NCH_A = HALO * 4;           // A 16B chunks per kc
    constexpr int NCH_B = 9 * 2 * 2 * 64;     // 2304 B 16B chunks per kc
    const int tid  = threadIdx.x;
    const int lane = tid & 63;
    const int wv   = tid >> 6;
    const int b     = blockIdx.y;
    const int patch = blockIdx.x;
    const int y0 = (patch >> 3) * PROWS;
    const int x0 = (patch & 7) * 16;
    const int ocBase = blockIdx.z * 64;

    __shared__ __align__(16) bf16_t s_a[HALO * PSTR];
    __shared__ __align__(16) bf16_t s_b[NCH_B * 8];

    f32x16 acc[MT][2];
#pragma unroll
    for (int mt = 0; mt < MT; ++mt)
#pragma unroll
        for (int nt = 0; nt < 2; ++nt)
#pragma unroll
            for (int r = 0; r < 16; ++r) acc[mt][nt][r] = 0.0f;

    const int m     = lane & 31;
    const int klane = lane >> 5;
    const int row0  = wv * 2 * MT + (m >> 4);
    const int pxx   = m & 15;
    int abase[MT];
#pragma unroll
    for (int mt = 0; mt < MT; ++mt)
        abase[mt] = ((row0 + 2*mt) * 18 + pxx) * PSTR + klane * 8;

    const bf16_t* Ab = A + (size_t)b * PSZ * 2 * CINP;

    for (int kc = 0; kc < NKC; ++kc) {
        __syncthreads();
        // stage B slice ASYNC (global->LDS DMA)
        {
            const bf16_t* wsrc = Wp + ((size_t)(blockIdx.z * NKC + kc) * NCH_B) * 8;
#pragma unroll
            for (int i = tid; i < NCH_B; i += 256)
                __builtin_amdgcn_global_load_lds(
                    (const __attribute__((address_space(1))) void*)(wsrc + i * 8),
                    (__attribute__((address_space(3))) void*)(s_b + i * 8),
                    16, 0, 0);
        }
        // stage A halo k-chunk (manual; overlaps B DMA)
        for (int i = tid; i < NCH_A; i += 256) {
            int pix = i >> 2, sub = i & 3;
            int pl = sub >> 1, half = sub & 1;
            int hy = pix / 18, hx = pix - hy * 18;
            const bf16_t* src = Ab + ((size_t)((y0 + hy) * PW + x0 + hx) * 2 + pl) * CINP
                                + kc * 16 + half * 8;
            *(bf16x8*)(s_a + pix * PSTR + pl * 16 + half * 8) = *(const bf16x8*)src;
        }
        __syncthreads();

#pragma unroll
        for (int tap = 0; tap < 9; ++tap) {
            const int aoff = ((tap / 3) * 18 + (tap % 3)) * PSTR;
            bf16x8 Bh[2], Bl[2];
#pragma unroll
            for (int nt = 0; nt < 2; ++nt) {
                Bh[nt] = *(const bf16x8*)(s_b + (((tap*2 + 0)*2 + klane)*64 + nt*32 + m)*8);
                Bl[nt] = *(const bf16x8*)(s_b + (((tap*2 + 1)*2 + klane)*64 + nt*32 + m)*8);
            }
#pragma unroll
            for (int mt = 0; mt < MT; ++mt) {
                bf16x8 Ah = *(const bf16x8*)(s_a + abase[mt] + aoff);
                bf16x8 Al = *(const bf16x8*)(s_a + abase[mt] + aoff + 16);
#pragma unroll
                for (int nt = 0; nt < 2; ++nt) {
                    acc[mt][nt] = __builtin_amdgcn_mfma_f32_32x32x16_bf16(Ah, Bh[nt], acc[mt][nt], 0,0,0);
                    acc[mt][nt] = __builtin_amdgcn_mfma_f32_32x32x16_bf16(Al, Bh[nt], acc[mt][nt], 0,0,0);
                    acc[mt][nt] = __builtin_amdgcn_mfma_f32_32x32x16_bf16(Ah, Bl[nt], acc[mt][nt], 0,0,0);
                }
            }
        }
    }

#pragma unroll
    for (int nt = 0; nt < 2; ++nt) {
        const int oc = ocBase + nt * 32 + m;
        if (EPI == 1 && oc >= OC) continue;
        const float bv = bias[oc];
#pragma unroll
        for (int mt = 0; mt < MT; ++mt) {
#pragma unroll
            for (int r = 0; r < 16; ++r) {
                const int row = (r & 3) + 8 * (r >> 2) + 4 * klane;
                const int pyy = wv * 2 * MT + mt * 2 + (row >> 4);
                const int gy = y0 + pyy, gx = x0 + (row & 15);
                float v = acc[mt][nt][r] + bv;
                if (EPI == 0) {
                    v = lrelu_f(v);
                    bf16_t h, l; split_bf16(v, h, l);
                    bf16_t* o = (bf16_t*)outv;
                    size_t base = ((size_t)(b * PSZ + (gy + 1) * PW + (gx + 1))) * 128 + oc;
                    o[base]      = h;
                    o[base + 64] = l;
                } else {
                    __half* o = (__half*)outv;
                    if (oc < 288) {
                        const int fch = (oc & 1) ^ 1;
                        float fl = flow[(size_t)(b*2 + fch) * HWSZ + gy * WW + gx];
                        v = 10.0f * tanhf(v) + fl;
                    } else {
                        v = 1.0f / (1.0f + expf(-v));
                    }
                    o[((size_t)(b * 432 + oc) << 14) + gy * WW + gx] = __float2half(v);
                }
            }
        }
    }
}

// ---------------------------------------------------------------------------
// dcn as gather-into-MFMA-fragments; off4 now fp16.
// ---------------------------------------------------------------------------
__global__ __launch_bounds__(256, 2)
void dcn_mfma_k(const float* __restrict__ xT, const __half* __restrict__ off4,
                const bf16_t* __restrict__ Bp, const float* __restrict__ bias,
                float* __restrict__ out)
{
    const int tid   = threadIdx.x;
    const int lane  = tid & 63;
    const int wv    = tid >> 6;
    const int klane = lane >> 5;
    const int m     = lane & 31;
    const int b     = blockIdx.z;
    const int tx0 = blockIdx.x * 16, ty0 = blockIdx.y * 8;
    const int py = ty0 + wv * 2 + (m >> 4);
    const int px = tx0 + (m & 15);
    const int pixoff = py * WW + px;

    const __half* offb = off4 + (size_t)b * 432 * HWSZ;
    const float*  xTb  = xT   + (size_t)b * HWSZ * 64;

    f32x16 acc[2];
#pragma unroll
    for (int nt = 0; nt < 2; ++nt)
#pragma unroll
        for (int r = 0; r < 16; ++r) acc[nt][r] = 0.0f;

    for (int dg = 0; dg < 16; ++dg) {
        bf16x8 Ah[3], Al[3];
#pragma unroll
        for (int ks = 0; ks < 3; ++ks) {
            float sv[8];
#pragma unroll
            for (int j = 0; j < 8; ++j) sv[j] = 0.0f;
#pragma unroll
            for (int tt = 0; tt < 2; ++tt) {
                const int tap = ks * 4 + klane * 2 + tt;
                if (tap < 9) {
                    const int ch = dg * 9 + tap;
                    float oy = __half2float(offb[(size_t)(2*ch    ) * HWSZ + pixoff]);
                    float ox = __half2float(offb[(size_t)(2*ch + 1) * HWSZ + pixoff]);
                    float mk = __half2float(offb[(size_t)(288 + ch) * HWSZ + pixoff]);
                    float ys = (float)py + (float)(tap / 3 - 1) + oy;
                    float xs = (float)px + (float)(tap % 3 - 1) + ox;
                    float y0f = floorf(ys), x0f = floorf(xs);
                    float wy = ys - y0f,    wx = xs - x0f;
                    int y0 = (int)y0f, x0i = (int)x0f;
                    int y1 = y0 + 1,   x1  = x0i + 1;
                    float fy0 = (y0  >= 0 && y0  < HH) ? 1.0f : 0.0f;
                    float fy1 = (y1  >= 0 && y1  < HH) ? 1.0f : 0.0f;
                    float fx0 = (x0i >= 0 && x0i < WW) ? 1.0f : 0.0f;
                    float fx1 = (x1  >= 0 && x1  < WW) ? 1.0f : 0.0f;
                    int yc0 = min(max(y0, 0), HH-1), yc1 = min(max(y1, 0), HH-1);
                    int xc0 = min(max(x0i,0), WW-1), xc1 = min(max(x1, 0), WW-1);
                    float w00 = (1.0f-wy)*(1.0f-wx)*fy0*fx0*mk;
                    float w01 = (1.0f-wy)*wx       *fy0*fx1*mk;
                    float w10 = wy       *(1.0f-wx)*fy1*fx0*mk;
                    float w11 = wy       *wx       *fy1*fx1*mk;
                    const float* p00 = xTb + ((size_t)(yc0*WW + xc0) * 64 + dg*4);
                    const float* p01 = xTb + ((size_t)(yc0*WW + xc1) * 64 + dg*4);
                    const float* p10 = xTb + ((size_t)(yc1*WW + xc0) * 64 + dg*4);
                    const float* p11 = xTb + ((size_t)(yc1*WW + xc1) * 64 + dg*4);
                    float4 c00 = *(const float4*)p00;
                    float4 c01 = *(const float4*)p01;
                    float4 c10 = *(const float4*)p10;
                    float4 c11 = *(const float4*)p11;
                    sv[tt*4+0] = c00.x*w00 + c01.x*w01 + c10.x*w10 + c11.x*w11;
                    sv[tt*4+1] = c00.y*w00 + c01.y*w01 + c10.y*w10 + c11.y*w11;
                    sv[tt*4+2] = c00.z*w00 + c01.z*w01 + c10.z*w10 + c11.z*w11;
                    sv[tt*4+3] = c00.w*w00 + c01.w*w01 + c10.w*w10 + c11.w*w11;
                }
            }
            bf16x8 h, l;
#pragma unroll
            for (int j = 0; j < 8; ++j) {
                bf16_t hh, ll; split_bf16(sv[j], hh, ll);
                h[j] = hh; l[j] = ll;
            }
            Ah[ks] = h; Al[ks] = l;
        }
        const bf16_t* bbase = Bp + (size_t)(dg * 3) * 64 * 2 * 16;
#pragma unroll
        for (int ks = 0; ks < 3; ++ks) {
#pragma unroll
            for (int nt = 0; nt < 2; ++nt) {
                const bf16_t* bp = bbase + ((size_t)(ks*64 + nt*32 + m) * 2) * 16 + klane*8;
                bf16x8 Bh = *(const bf16x8*)bp;
                bf16x8 Bl = *(const bf16x8*)(bp + 16);
                acc[nt] = __builtin_amdgcn_mfma_f32_32x32x16_bf16(Ah[ks], Bh, acc[nt], 0,0,0);
                acc[nt] = __builtin_amdgcn_mfma_f32_32x32x16_bf16(Al[ks], Bh, acc[nt], 0,0,0);
                acc[nt] = __builtin_amdgcn_mfma_f32_32x32x16_bf16(Ah[ks], Bl, acc[nt], 0,0,0);
            }
        }
    }

#pragma unroll
    for (int nt = 0; nt < 2; ++nt) {
        const int oc = nt * 32 + m;
        const float bv = bias[oc];
#pragma unroll
        for (int r = 0; r < 16; ++r) {
            const int row = (r & 3) + 8 * (r >> 2) + 4 * klane;
            const int gy = ty0 + wv * 2 + (row >> 4);
            const int gx = tx0 + (row & 15);
            out[((size_t)(b*64 + oc) << 14) + gy * WW + gx] = acc[nt][r] + bv;
        }
    }
}

// ---------------------------------------------------------------------------
// Workspace (~76 MB):
//   [0, 56.6MB)   off4h (fp16). Aliased during conv chain:
//       A0  @ +0      (38.9MB, live pack_a0..conv1)
//       h2p @ +0      (17.3MB, live conv2..conv3; borders zeroed AFTER conv1)
//   [56.6, 73.9MB) h1p (borders zeroed first; xT aliases it after conv4)
//   [73.9MB, ...)  packed weights (wp1..wp4, Bp)
// ---------------------------------------------------------------------------
extern "C" void kernel_launch(void* const* d_in, const int* in_sizes, int n_in,
                              void* d_out, int out_size, void* d_ws, size_t ws_size,
                              hipStream_t stream)
{
    const float* x    = (const float*)d_in[0];
    const float* xfw  = (const float*)d_in[1];
    const float* xc   = (const float*)d_in[2];
    const float* flow = (const float*)d_in[3];
    const float* w1 = (const float*)d_in[4];  const float* b1 = (const float*)d_in[5];
    const float* w2 = (const float*)d_in[6];  const float* b2 = (const float*)d_in[7];
    const float* w3 = (const float*)d_in[8];  const float* b3 = (const float*)d_in[9];
    const float* w4 = (const float*)d_in[10]; const float* b4 = (const float*)d_in[11];
    const float* dw = (const float*)d_in[12]; const float* db = (const float*)d_in[13];

    char* wsb = (char*)d_ws;
    const size_t off4_bytes = (size_t)BB * 432 * HWSZ * 2;      // 56,623,104 (fp16)
    __half* off4 = (__half*)wsb;
    bf16_t* A0   = (bf16_t*)wsb;                                // live pack_a0..conv1
    bf16_t* h2p  = (bf16_t*)wsb;                                // live conv2..conv3
    char* p = wsb + off4_bytes;
    bf16_t* h1p = (bf16_t*)p;  float* xT = (float*)h1p;         // xT aliases h1p post-conv4
                               p += (size_t)BB * PSZ * 2 * 64 * 2;
    bf16_t* wp1 = (bf16_t*)p;  p += (size_t)64  * 144 * 18 * 2;
    bf16_t* wp2 = (bf16_t*)p;  p += (size_t)64  * 64  * 18 * 2;
    bf16_t* wp3 = (bf16_t*)p;  p += (size_t)64  * 64  * 18 * 2;
    bf16_t* wp4 = (bf16_t*)p;  p += (size_t)448 * 64  * 18 * 2;
    bf16_t* Bp  = (bf16_t*)p;  p += (size_t)16 * 3 * 64 * 2 * 16 * 2;

    zero_border_k<<<(2064*16 + 255)/256, 256, 0, stream>>>(h1p);
    pack_w_k<<<(64*144*18 + 255)/256, 256, 0, stream>>>(w1, wp1, 64, 130, 64, 144, 9);
    pack_w_k<<<(64*64*18  + 255)/256, 256, 0, stream>>>(w2, wp2, 64, 64, 64, 64, 4);
    pack_w_k<<<(64*64*18  + 255)/256, 256, 0, stream>>>(w3, wp3, 64, 64, 64, 64, 4);
    pack_w_k<<<(448*64*18 + 255)/256, 256, 0, stream>>>(w4, wp4, 432, 64, 448, 64, 4);
    pack_dw_k<<<(16*48*64 + 255)/256, 256, 0, stream>>>(dw, Bp);
    pack_a0_k<<<(BB*PSZ + 63)/64, 256, 0, stream>>>(xfw, xc, flow, A0);

    // conv chain: all MT=1 (3 blocks/CU), B staged async in LDS
    conv_mfma_k<144,1,0><<<dim3(128, BB, 1), 256, 0, stream>>>(A0,  wp1, b1, h1p, 64,  nullptr);
    zero_border_k<<<(2064*16 + 255)/256, 256, 0, stream>>>(h2p);   // A0 dead now
    conv_mfma_k<64, 1,0><<<dim3(128, BB, 1), 256, 0, stream>>>(h1p, wp2, b2, h2p, 64,  nullptr);
    conv_mfma_k<64, 1,0><<<dim3(128, BB, 1), 256, 0, stream>>>(h2p, wp3, b3, h1p, 64,  nullptr);
    conv_mfma_k<64, 1,1><<<dim3(128, BB, 7), 256, 0, stream>>>(h1p, wp4, b4, off4, 432, flow);
    // xT overwrites h1p (dead after conv4)
    pack_xt_k<<<BB * HWSZ / 64, 256, 0, stream>>>(x, xT);

    dcn_mfma_k<<<dim3(8, 16, BB), 256, 0, stream>>>(xT, off4, Bp, db, (float*)d_out);
}